// Round 8
// baseline (3360.915 us; speedup 1.0000x reference)
//
#include <hip/hip_runtime.h>
#include <math.h>

#define B_  32
#define S_  512
#define H_  1024
#define G3_ 3072
#define SENT32 0x7F7F7F7Fu   // bf16 0x7F7F ~ 3.39e38; |h|<1 so unreachable

typedef __attribute__((ext_vector_type(8))) short bf16x8;   // 8 bf16 in 4 VGPRs
typedef __attribute__((ext_vector_type(4))) float f32x4;
typedef __attribute__((ext_vector_type(4))) unsigned int u32x4;

__device__ __forceinline__ unsigned short f2bf(float f) {
  unsigned int u = __float_as_uint(f);
  u = (u + 0x7FFFu + ((u >> 16) & 1u)) >> 16;   // RNE
  return (unsigned short)u;
}

// 16B load, bypass L1 AND L2 (sc0 sc1) -> MALL, agent-coherent. Issued
// without any waitcnt; caller batches many then waits ONCE.
__device__ __forceinline__ void ld4_mall(const unsigned short* p, u32x4& r) {
  asm volatile("global_load_dwordx4 %0, %1, off sc0 sc1" : "=v"(r) : "v"(p));
}
// 4B store, agent-coherent (MALL). Fire-and-forget; its ack is only ever
// awaited inside a subsequent poll's vmcnt(0), never at a barrier.
__device__ __forceinline__ void st_mall_b32(unsigned short* p, unsigned int v) {
  asm volatile("global_store_dword %0, %1, off sc0 sc1" :: "v"(p), "v"(v) : "memory");
}

// Workgroup barrier that drains ONLY lgkmcnt (LDS), not vmcnt: y-store acks
// and in-flight poll loads stay outstanding across it.
#define BAR_LGKM() do {                                   \
  __builtin_amdgcn_sched_barrier(0);                      \
  asm volatile("s_waitcnt lgkmcnt(0)" ::: "memory");      \
  __builtin_amdgcn_s_barrier();                           \
  __builtin_amdgcn_sched_barrier(0);                      \
} while (0)

__global__ void cast_f32_bf16(const float* __restrict__ in, unsigned short* __restrict__ out, int n) {
  int i = blockIdx.x * 256 + threadIdx.x;
  if (i < n) out[i] = f2bf(in[i]);
}

// x (B,S,512) fp32 -> xtm (S,B,512) bf16
__global__ void cast_transpose_x(const float* __restrict__ x, unsigned short* __restrict__ xtm) {
  int s = blockIdx.x & 511, b = blockIdx.x >> 9;   // grid 16384
  int k = threadIdx.x * 4;                          // 128 threads
  float4 v = *(const float4*)(x + ((size_t)b * S_ + s) * 512 + k);
  ushort4 o = { f2bf(v.x), f2bf(v.y), f2bf(v.z), f2bf(v.w) };
  *(ushort4*)(xtm + ((size_t)s * B_ + b) * 512 + k) = o;
}

// ---------------- big GEMM (verified; used for final projection) ----------------
template<int APERM, int CPERM, typename CT>
__global__ __launch_bounds__(256)
void gemm_bf16(const unsigned short* __restrict__ A, const unsigned short* __restrict__ W,
               const float* __restrict__ bias, CT* __restrict__ C, int M, int N, int K) {
  __shared__ __align__(16) unsigned short As[128 * 40];
  __shared__ __align__(16) unsigned short Ws[128 * 40];
  const int tid   = threadIdx.x;
  const int mBase = blockIdx.y * 128;
  const int nBase = blockIdx.x * 128;
  const int lane  = tid & 63;
  const int w     = tid >> 6;
  const int wm    = (w & 1) * 64;
  const int wn    = (w >> 1) * 64;
  const int r16   = lane & 15;
  const int q     = lane >> 4;

  f32x4 acc[4][4];
  for (int i = 0; i < 4; ++i)
    for (int j = 0; j < 4; ++j)
      for (int t = 0; t < 4; ++t) acc[i][j][t] = 0.f;

  const int r0  = tid >> 2;
  const int kk0 = (tid & 3) * 8;

  for (int k0 = 0; k0 < K; k0 += 32) {
    {
      int r = r0;
      size_t ar = APERM ? ((size_t)((mBase + r) & 31) * S_ + (size_t)((mBase + r) >> 5)) : (size_t)(mBase + r);
      *(uint4*)&As[r * 40 + kk0] = *(const uint4*)(A + ar * K + k0 + kk0);
      int r2 = r + 64;
      size_t ar2 = APERM ? ((size_t)((mBase + r2) & 31) * S_ + (size_t)((mBase + r2) >> 5)) : (size_t)(mBase + r2);
      *(uint4*)&As[r2 * 40 + kk0] = *(const uint4*)(A + ar2 * K + k0 + kk0);
      *(uint4*)&Ws[r * 40 + kk0]  = *(const uint4*)(W + (size_t)(nBase + r)  * K + k0 + kk0);
      *(uint4*)&Ws[r2 * 40 + kk0] = *(const uint4*)(W + (size_t)(nBase + r2) * K + k0 + kk0);
    }
    __syncthreads();
    bf16x8 af[4], bfr[4];
#pragma unroll
    for (int i = 0; i < 4; ++i) af[i]  = *(const bf16x8*)&As[(wm + i * 16 + r16) * 40 + q * 8];
#pragma unroll
    for (int j = 0; j < 4; ++j) bfr[j] = *(const bf16x8*)&Ws[(wn + j * 16 + r16) * 40 + q * 8];
#pragma unroll
    for (int i = 0; i < 4; ++i)
#pragma unroll
      for (int j = 0; j < 4; ++j)
        acc[i][j] = __builtin_amdgcn_mfma_f32_16x16x32_bf16(af[i], bfr[j], acc[i][j], 0, 0, 0);
    __syncthreads();
  }

#pragma unroll
  for (int i = 0; i < 4; ++i)
#pragma unroll
    for (int j = 0; j < 4; ++j)
#pragma unroll
      for (int t = 0; t < 4; ++t) {
        int m = mBase + wm + i * 16 + q * 4 + t;
        int n = nBase + wn + j * 16 + r16;
        float v = acc[i][j][t] + bias[n];
        size_t crow = CPERM ? ((size_t)(m & 31) * S_ + (size_t)(m >> 5)) : (size_t)m;
        if constexpr (sizeof(CT) == 4) C[crow * N + n] = v;
        else                           C[crow * N + n] = f2bf(v);
      }
}

// ---------------- fused 2-layer persistent GRU, batch-split pipelined ----------------
// 128 blocks x 512 threads (8 waves). Blocks 0-63: layer 0; 64-127: layer 1.
// Block owns j-slice [j0,j0+16) of all 3 gates; waves 0-3 x-part, 4-7 h-part.
// SYNC (R5/R7 mechanism): y poisoned 0x7F; consumers fetch A-fragments as
// batched MALL loads + ONE vmcnt(0), check against the sentinel.
// THIS ROUND: the GRU recurrence is independent across batch rows, so B=32 is
// split into TWO halves (rows 0-15 / 16-31) run as interleaved phases in the
// same block. While half-A's h-store propagates through the MALL, the block
// computes half-B -- a full phase (~compute+epilogue) elapses between a
// half's store and its next poll, so the exchange latency is hidden instead
// of exposed. Per phase: M=16 (one m-tile, acc[3]), part[] 24KB/phase (2x),
// 256-thread epilogue, 1 output/thread. Deadlock-free: polls only target
// strictly-earlier data; producers never depend on their consumers.

__global__ __launch_bounds__(512, 2)
void gru_fused(const unsigned short* __restrict__ wih0, const unsigned short* __restrict__ whh0,
               const float* __restrict__ b0,
               const unsigned short* __restrict__ wih1, const unsigned short* __restrict__ whh1,
               const float* __restrict__ b1,
               const unsigned short* __restrict__ xtm, const unsigned short* __restrict__ zerosB,
               unsigned short* __restrict__ y0, unsigned short* __restrict__ y1,
               float* __restrict__ hlast0, float* __restrict__ hlast1) {
  __shared__ __align__(16) float part[2][8 * 3 * 64 * 4];   // [half][w][g][lane][reg] 2x24KB
  const int tid  = threadIdx.x;
  const int lane = tid & 63;
  const int w    = tid >> 6;          // 0..7
  const int r16  = lane & 15;
  const int q    = lane >> 4;
  const bool L1  = blockIdx.x >= 64;
  const int  j0  = (L1 ? (int)blockIdx.x - 64 : (int)blockIdx.x) * 16;
  const bool hiw = w >= 4;

  // per-wave operand plan
  const unsigned short* Wsrc;
  int wstride, kbase, ncha;
  if (!L1) {
    if (!hiw) { Wsrc = wih0; wstride = 512;  kbase = w * 128;       ncha = 4; }
    else      { Wsrc = whh0; wstride = 1024; kbase = (w - 4) * 256; ncha = 8; }
  } else {
    if (!hiw) { Wsrc = wih1; wstride = 1024; kbase = w * 256;       ncha = 8; }
    else      { Wsrc = whh1; wstride = 1024; kbase = (w - 4) * 256; ncha = 8; }
  }

  // B-frags -> registers, once
  bf16x8 bw[3][8];
#pragma unroll
  for (int g = 0; g < 3; ++g)
#pragma unroll
    for (int c = 0; c < 8; ++c)
      if (c < ncha)
        bw[g][c] = *(const bf16x8*)(Wsrc + (size_t)(g * H_ + j0 + r16) * wstride + kbase + c * 32 + q * 8);

  // epilogue coords: 256 threads, 1 output (half-batch eb2, feature ejj) per phase
  const int eb2   = (tid >> 4) & 15;  // 0..15 (batch row within half)
  const int ejj   = tid & 15;         // 0..15 (feature within j-slice)
  const int elane = (eb2 >> 2) * 16 + ejj;
  const int ereg  = eb2 & 3;
  const float* bias = L1 ? b1 : b0;
  const float brv = bias[j0 + ejj];
  const float bzv = bias[H_ + j0 + ejj];
  const float bnv = bias[2 * H_ + j0 + ejj];
  float phv[2] = {0.f, 0.f};          // running h per half (static-indexed via unroll)

  unsigned short* ybuf  = L1 ? y1 : y0;
  float*          hlast = L1 ? hlast1 : hlast0;

  for (int t = 0; t < S_; ++t) {
#pragma unroll
    for (int half = 0; half < 2; ++half) {
      // ---- A-frags for this half (16 rows) ----
      const unsigned short* Asrc;
      int astride; bool plainA;
      if (!hiw) {
        if (!L1) { Asrc = xtm + (size_t)t * B_ * 512 + (size_t)half * 16 * 512; astride = 512;  plainA = true; }
        else     { Asrc = y0  + (size_t)t * B_ * H_  + (size_t)half * 16 * H_;  astride = 1024; plainA = false; }
      } else {
        if (t) { Asrc = ybuf + (size_t)(t - 1) * B_ * H_ + (size_t)half * 16 * H_; astride = 1024; plainA = false; }
        else   { Asrc = zerosB; astride = 1024; plainA = true; }
      }
      union AU { unsigned int dd[4]; u32x4 u4; bf16x8 v; };
      AU a0[8];
      const unsigned short* ap0 = Asrc + (size_t)r16 * astride + kbase + q * 8;
      if (plainA) {
#pragma unroll
        for (int c = 0; c < 8; ++c) if (c < ncha)
          a0[c].v = *(const bf16x8*)(ap0 + c * 32);
      } else {
        // polled waves always have ncha==8. Batched agent-coherent fetch:
        // 8 loads in flight -> ONE waitcnt -> check. ~1 MALL RT per iteration.
        // A full other-half phase has elapsed since the producers stored, so
        // the first iteration usually succeeds.
        int spins = 0;
        for (;;) {
#pragma unroll
          for (int c = 0; c < 8; ++c) ld4_mall(ap0 + c * 32, a0[c].u4);
          asm volatile("s_waitcnt vmcnt(0)"
            : "+v"(a0[0].u4), "+v"(a0[1].u4), "+v"(a0[2].u4), "+v"(a0[3].u4),
              "+v"(a0[4].u4), "+v"(a0[5].u4), "+v"(a0[6].u4), "+v"(a0[7].u4)
            :: "memory");
          __builtin_amdgcn_sched_barrier(0);
          int ok = 1;
#pragma unroll
          for (int c = 0; c < 8; ++c)
#pragma unroll
            for (int d = 0; d < 4; ++d)
              ok &= (a0[c].dd[d] != SENT32);
          if (__all(ok)) break;
          if (++spins > (1 << 20)) break;    // hang-safety only
          if (spins > 8) __builtin_amdgcn_s_sleep(1);
        }
      }

      // ---- MFMA: one M-tile, 3 gates ----
      f32x4 acc[3];
#pragma unroll
      for (int g = 0; g < 3; ++g)
#pragma unroll
        for (int u = 0; u < 4; ++u) acc[g][u] = 0.f;

#pragma unroll
      for (int c = 0; c < 8; ++c) if (c < ncha)
#pragma unroll
        for (int g = 0; g < 3; ++g)
          acc[g] = __builtin_amdgcn_mfma_f32_16x16x32_bf16(a0[c].v, bw[g][c], acc[g], 0, 0, 0);

      float* pb = part[half];
#pragma unroll
      for (int g = 0; g < 3; ++g)
        *(f32x4*)&pb[((w * 3 + g) * 64 + lane) * 4] = acc[g];
      BAR_LGKM();                     // LDS writes visible; no vmem drain

      // ---- epilogue: 256 threads x 1 output; packed u32 store is the signal ----
      if (tid < 256) {
        unsigned short* yt = ybuf + (size_t)t * (B_ * H_) + (size_t)half * 16 * H_;
        float hr = 0.f, hz = 0.f, nx = 0.f, nh = 0.f;
#pragma unroll
        for (int ww = 0; ww < 8; ++ww) {
          float vr = pb[((ww * 3 + 0) * 64 + elane) * 4 + ereg];
          float vz = pb[((ww * 3 + 1) * 64 + elane) * 4 + ereg];
          float vn = pb[((ww * 3 + 2) * 64 + elane) * 4 + ereg];
          hr += vr; hz += vz;
          if (ww < 4) nx += vn; else nh += vn;
        }
        float r  = __builtin_amdgcn_rcpf(1.f + __expf(-(hr + brv)));
        float z  = __builtin_amdgcn_rcpf(1.f + __expf(-(hz + bzv)));
        float a2 = nx + bnv + nh + r * nh;
        float nn = 1.f - 2.f * __builtin_amdgcn_rcpf(__expf(2.f * a2) + 1.f);  // tanh
        float hv = (1.f - z) * nn + z * phv[half];
        phv[half] = hv;
        float other = __shfl_xor(hv, 1);   // partner tid^1 = same batch, ejj^1
        if ((ejj & 1) == 0) {
          unsigned int pk = (unsigned int)f2bf(hv) | ((unsigned int)f2bf(other) << 16);
          st_mall_b32(yt + (size_t)eb2 * H_ + j0 + ejj, pk);  // one writer per u32
          if (t == S_ - 1) {
            hlast[(half * 16 + eb2) * H_ + j0 + ejj]     = hv;
            hlast[(half * 16 + eb2) * H_ + j0 + ejj + 1] = other;
          }
        }
      }
      BAR_LGKM();                     // part[half] reads done; acks NOT drained
    }
  }
}

extern "C" void kernel_launch(void* const* d_in, const int* in_sizes, int n_in,
                              void* d_out, int out_size, void* d_ws, size_t ws_size,
                              hipStream_t stream) {
  const float* x    = (const float*)d_in[0];
  const float* Wih0 = (const float*)d_in[1];
  const float* Whh0 = (const float*)d_in[2];
  const float* b0   = (const float*)d_in[3];
  const float* Wih1 = (const float*)d_in[4];
  const float* Whh1 = (const float*)d_in[5];
  const float* b1   = (const float*)d_in[6];
  const float* Wlin = (const float*)d_in[7];
  const float* blin = (const float*)d_in[8];
  float* out = (float*)d_out;

  char* p = (char*)d_ws;
  size_t off = 0;
  auto alloc = [&](size_t bytes) { void* r = p + off; off += (bytes + 255) & ~(size_t)255; return r; };

  unsigned short* xtm   = (unsigned short*)alloc((size_t)8388608 * 2);   // (S,B,512) bf16
  unsigned short* wih0b = (unsigned short*)alloc((size_t)1572864 * 2);
  unsigned short* whh0b = (unsigned short*)alloc((size_t)3145728 * 2);
  unsigned short* wih1b = (unsigned short*)alloc((size_t)3145728 * 2);
  unsigned short* whh1b = (unsigned short*)alloc((size_t)3145728 * 2);
  unsigned short* wlinb = (unsigned short*)alloc((size_t)524288 * 2);
  unsigned short* y0b   = (unsigned short*)alloc((size_t)16777216 * 2);  // (S,B,H) bf16
  unsigned short* y1b   = (unsigned short*)alloc((size_t)16777216 * 2);
  unsigned short* zerosB= (unsigned short*)alloc((size_t)B_ * H_ * 2);

  // poison y buffers: 0x7F7F bf16 sentinel (unreachable since |h|<1)
  (void)hipMemsetAsync(y0b, 0x7F, (size_t)16777216 * 2, stream);
  (void)hipMemsetAsync(y1b, 0x7F, (size_t)16777216 * 2, stream);
  (void)hipMemsetAsync(zerosB, 0, (size_t)B_ * H_ * 2, stream);

  auto cast = [&](const float* in, unsigned short* o, int n) {
    cast_f32_bf16<<<n / 256, 256, 0, stream>>>(in, o, n);
  };
  cast_transpose_x<<<16384, 128, 0, stream>>>(x, xtm);
  cast(Wih0, wih0b, 1572864);
  cast(Whh0, whh0b, 3145728);
  cast(Wih1, wih1b, 3145728);
  cast(Whh1, whh1b, 3145728);
  cast(Wlin, wlinb, 524288);

  float* hlast0 = out + 8388608;
  float* hlast1 = out + 8388608 + B_ * H_;

  gru_fused<<<128, 512, 0, stream>>>(wih0b, whh0b, b0, wih1b, whh1b, b1,
                                     xtm, zerosB, y0b, y1b, hlast0, hlast1);

  // final: out = y1 @ Wlin^T + blin, C rows -> (b,s)
  {
    dim3 g(512 / 128, 16384 / 128);
    gemm_bf16<0, 1, float><<<g, 256, 0, stream>>>(y1b, wlinb, blin, out, 16384, 512, 1024);
  }
}

// Round 9
// 1893.198 us; speedup vs baseline: 1.7753x; 1.7753x over previous
//
#include <hip/hip_runtime.h>
#include <math.h>

#define B_  32
#define S_  512
#define H_  1024
#define G3_ 3072
#define SENT32 0x7F7F7F7Fu   // bf16 0x7F7F ~ 3.39e38; |h|<1 so unreachable

typedef __attribute__((ext_vector_type(8))) short bf16x8;   // 8 bf16 in 4 VGPRs
typedef __attribute__((ext_vector_type(4))) float f32x4;
typedef __attribute__((ext_vector_type(4))) unsigned int u32x4;

__device__ __forceinline__ unsigned short f2bf(float f) {
  unsigned int u = __float_as_uint(f);
  u = (u + 0x7FFFu + ((u >> 16) & 1u)) >> 16;   // RNE
  return (unsigned short)u;
}

// 16B load, bypass L1 AND L2 (sc0 sc1) -> MALL, agent-coherent. Issued
// without any waitcnt; caller batches many then waits ONCE.
__device__ __forceinline__ void ld4_mall(const unsigned short* p, u32x4& r) {
  asm volatile("global_load_dwordx4 %0, %1, off sc0 sc1" : "=v"(r) : "v"(p));
}
// 4B store, agent-coherent (MALL). Fire-and-forget; its ack is only ever
// awaited inside a subsequent poll's vmcnt(0), never at a barrier.
__device__ __forceinline__ void st_mall_b32(unsigned short* p, unsigned int v) {
  asm volatile("global_store_dword %0, %1, off sc0 sc1" :: "v"(p), "v"(v) : "memory");
}

// Workgroup barrier that drains ONLY lgkmcnt (LDS), not vmcnt: y-store acks
// and in-flight poll loads stay outstanding across it.
#define BAR_LGKM() do {                                   \
  __builtin_amdgcn_sched_barrier(0);                      \
  asm volatile("s_waitcnt lgkmcnt(0)" ::: "memory");      \
  __builtin_amdgcn_s_barrier();                           \
  __builtin_amdgcn_sched_barrier(0);                      \
} while (0)

__global__ void cast_f32_bf16(const float* __restrict__ in, unsigned short* __restrict__ out, int n) {
  int i = blockIdx.x * 256 + threadIdx.x;
  if (i < n) out[i] = f2bf(in[i]);
}

// x (B,S,512) fp32 -> xtm (S,B,512) bf16
__global__ void cast_transpose_x(const float* __restrict__ x, unsigned short* __restrict__ xtm) {
  int s = blockIdx.x & 511, b = blockIdx.x >> 9;   // grid 16384
  int k = threadIdx.x * 4;                          // 128 threads
  float4 v = *(const float4*)(x + ((size_t)b * S_ + s) * 512 + k);
  ushort4 o = { f2bf(v.x), f2bf(v.y), f2bf(v.z), f2bf(v.w) };
  *(ushort4*)(xtm + ((size_t)s * B_ + b) * 512 + k) = o;
}

// ---------------- big GEMM (verified; used for final projection) ----------------
template<int APERM, int CPERM, typename CT>
__global__ __launch_bounds__(256)
void gemm_bf16(const unsigned short* __restrict__ A, const unsigned short* __restrict__ W,
               const float* __restrict__ bias, CT* __restrict__ C, int M, int N, int K) {
  __shared__ __align__(16) unsigned short As[128 * 40];
  __shared__ __align__(16) unsigned short Ws[128 * 40];
  const int tid   = threadIdx.x;
  const int mBase = blockIdx.y * 128;
  const int nBase = blockIdx.x * 128;
  const int lane  = tid & 63;
  const int w     = tid >> 6;
  const int wm    = (w & 1) * 64;
  const int wn    = (w >> 1) * 64;
  const int r16   = lane & 15;
  const int q     = lane >> 4;

  f32x4 acc[4][4];
  for (int i = 0; i < 4; ++i)
    for (int j = 0; j < 4; ++j)
      for (int t = 0; t < 4; ++t) acc[i][j][t] = 0.f;

  const int r0  = tid >> 2;
  const int kk0 = (tid & 3) * 8;

  for (int k0 = 0; k0 < K; k0 += 32) {
    {
      int r = r0;
      size_t ar = APERM ? ((size_t)((mBase + r) & 31) * S_ + (size_t)((mBase + r) >> 5)) : (size_t)(mBase + r);
      *(uint4*)&As[r * 40 + kk0] = *(const uint4*)(A + ar * K + k0 + kk0);
      int r2 = r + 64;
      size_t ar2 = APERM ? ((size_t)((mBase + r2) & 31) * S_ + (size_t)((mBase + r2) >> 5)) : (size_t)(mBase + r2);
      *(uint4*)&As[r2 * 40 + kk0] = *(const uint4*)(A + ar2 * K + k0 + kk0);
      *(uint4*)&Ws[r * 40 + kk0]  = *(const uint4*)(W + (size_t)(nBase + r)  * K + k0 + kk0);
      *(uint4*)&Ws[r2 * 40 + kk0] = *(const uint4*)(W + (size_t)(nBase + r2) * K + k0 + kk0);
    }
    __syncthreads();
    bf16x8 af[4], bfr[4];
#pragma unroll
    for (int i = 0; i < 4; ++i) af[i]  = *(const bf16x8*)&As[(wm + i * 16 + r16) * 40 + q * 8];
#pragma unroll
    for (int j = 0; j < 4; ++j) bfr[j] = *(const bf16x8*)&Ws[(wn + j * 16 + r16) * 40 + q * 8];
#pragma unroll
    for (int i = 0; i < 4; ++i)
#pragma unroll
      for (int j = 0; j < 4; ++j)
        acc[i][j] = __builtin_amdgcn_mfma_f32_16x16x32_bf16(af[i], bfr[j], acc[i][j], 0, 0, 0);
    __syncthreads();
  }

#pragma unroll
  for (int i = 0; i < 4; ++i)
#pragma unroll
    for (int j = 0; j < 4; ++j)
#pragma unroll
      for (int t = 0; t < 4; ++t) {
        int m = mBase + wm + i * 16 + q * 4 + t;
        int n = nBase + wn + j * 16 + r16;
        float v = acc[i][j][t] + bias[n];
        size_t crow = CPERM ? ((size_t)(m & 31) * S_ + (size_t)(m >> 5)) : (size_t)m;
        if constexpr (sizeof(CT) == 4) C[crow * N + n] = v;
        else                           C[crow * N + n] = f2bf(v);
      }
}

// ---------------- fused 2-layer persistent GRU, single-writer-line exchange ----------------
// 128 blocks x 512 threads (8 waves). Blocks 0-63: layer 0; 64-127: layer 1.
// Block owns j-slice [j0,j0+16) of all 3 gates; waves 0-3 x-part, 4-7 h-part.
// SYNC (R5/R7 mechanism, verified): exchange buffers poisoned 0x7F; consumers
// fetch A-fragments as 16 batched MALL loads + ONE vmcnt(0), sentinel-check.
// THIS ROUND: exchange layout hx[t][blk][b][16feat] -- each producer block
// owns a CONTIGUOUS line-aligned 1KB region per step (single-writer lines).
// The old [t][b][H] layout interleaved 4 blocks' 4B stores in every 128B
// line (false sharing at the MALL: line clears only when the last of 4 CUs'
// stores lands). Consumer mapping: col=kbase+c*32+q*8 -> block col>>4,
// feat col&15, addr blk*512 + row*16 + f -- same 16B loads, same count.
// L0 stores hx0 (polled by L0 h-waves @t-1, L1 x-waves @t). L1 stores hx1
// (polled by own h-waves) + plain y1 [t][b][H] for the final GEMM.

__global__ __launch_bounds__(512, 2)
void gru_fused(const unsigned short* __restrict__ wih0, const unsigned short* __restrict__ whh0,
               const float* __restrict__ b0,
               const unsigned short* __restrict__ wih1, const unsigned short* __restrict__ whh1,
               const float* __restrict__ b1,
               const unsigned short* __restrict__ xtm, const unsigned short* __restrict__ zerosB,
               unsigned short* __restrict__ hx0, unsigned short* __restrict__ hx1,
               unsigned short* __restrict__ y1,
               float* __restrict__ hlast0, float* __restrict__ hlast1) {
  __shared__ __align__(16) float part[8 * 2 * 3 * 64 * 4];   // 48 KB [w][m][g][lane][reg]
  const int tid  = threadIdx.x;
  const int lane = tid & 63;
  const int w    = tid >> 6;          // 0..7
  const int r16  = lane & 15;
  const int q    = lane >> 4;
  const bool L1  = blockIdx.x >= 64;
  const int  j0  = (L1 ? (int)blockIdx.x - 64 : (int)blockIdx.x) * 16;
  const int  myblk = j0 >> 4;
  const bool hiw = w >= 4;

  // per-wave operand plan
  const unsigned short* Wsrc;
  int wstride, kbase, ncha;
  if (!L1) {
    if (!hiw) { Wsrc = wih0; wstride = 512;  kbase = w * 128;       ncha = 4; }
    else      { Wsrc = whh0; wstride = 1024; kbase = (w - 4) * 256; ncha = 8; }
  } else {
    if (!hiw) { Wsrc = wih1; wstride = 1024; kbase = w * 256;       ncha = 8; }
    else      { Wsrc = whh1; wstride = 1024; kbase = (w - 4) * 256; ncha = 8; }
  }
  const int blkbase = kbase >> 4;     // hx block index base for this wave's K-slice

  // B-frags -> registers, once
  bf16x8 bw[3][8];
#pragma unroll
  for (int g = 0; g < 3; ++g)
#pragma unroll
    for (int c = 0; c < 8; ++c)
      if (c < ncha)
        bw[g][c] = *(const bf16x8*)(Wsrc + (size_t)(g * H_ + j0 + r16) * wstride + kbase + c * 32 + q * 8);

  // epilogue coords: 512 threads, 1 output (batch eb, feature ejj) each
  const int eb  = tid >> 4;       // 0..31
  const int ejj = tid & 15;       // 0..15
  const int em  = eb >> 4, eq2 = (eb >> 2) & 3, ereg = eb & 3;
  const float* bias = L1 ? b1 : b0;
  const float brv = bias[j0 + ejj];
  const float bzv = bias[H_ + j0 + ejj];
  const float bnv = bias[2 * H_ + j0 + ejj];
  float phv = 0.f;

  unsigned short* hxbuf = L1 ? hx1 : hx0;   // own-layer h exchange (store + h-poll)
  float*          hlast = L1 ? hlast1 : hlast0;

  // per-lane offset within an hx step-slab for polled fetch:
  // col = kbase + c*32 + q*8 -> blk = blkbase + c*2 + (q>>1), f0 = (q&1)*8
  // elem addr within slab = blk*512 + row*16 + f0 ; chunk c stride = 1024.
  const int hxLaneOff = ((q >> 1) * 512) + r16 * 16 + (q & 1) * 8;

  for (int t = 0; t < S_; ++t) {
    // ---- A-frags (self-synchronizing: poll data against sentinel) ----
    union AU { unsigned int dd[4]; u32x4 u4; bf16x8 v; };
    AU a0[8], a1[8];
    bool plain;
    const unsigned short* pp = nullptr;   // plain-fetch base (old layout)
    int pstride = 0;
    const unsigned short* hp = nullptr;   // polled-fetch base (hx layout)
    if (!hiw) {
      if (!L1) { plain = true;  pp = xtm + (size_t)t * B_ * 512; pstride = 512; }
      else     { plain = false; hp = hx0 + ((size_t)t * 64 + blkbase) * 512 + hxLaneOff; }
    } else {
      if (t == 0) { plain = true;  pp = zerosB; pstride = 1024; }
      else        { plain = false; hp = hxbuf + ((size_t)(t - 1) * 64 + blkbase) * 512 + hxLaneOff; }
    }
    if (plain) {
      const unsigned short* ap0 = pp + (size_t)r16 * pstride + kbase + q * 8;
      const unsigned short* ap1 = ap0 + 16 * pstride;
#pragma unroll
      for (int c = 0; c < 8; ++c) if (c < ncha) {
        a0[c].v = *(const bf16x8*)(ap0 + c * 32);
        a1[c].v = *(const bf16x8*)(ap1 + c * 32);
      }
    } else {
      // polled waves always have ncha==8. Batched agent-coherent fetch:
      // 16 loads in flight -> ONE waitcnt -> check. ~1 MALL RT per iteration.
      int spins = 0;
      for (;;) {
#pragma unroll
        for (int c = 0; c < 8; ++c) {
          ld4_mall(hp + c * 1024, a0[c].u4);          // rows 0-15 (r16)
          ld4_mall(hp + c * 1024 + 256, a1[c].u4);    // rows 16-31
        }
        asm volatile("s_waitcnt vmcnt(0)"
          : "+v"(a0[0].u4), "+v"(a0[1].u4), "+v"(a0[2].u4), "+v"(a0[3].u4),
            "+v"(a0[4].u4), "+v"(a0[5].u4), "+v"(a0[6].u4), "+v"(a0[7].u4),
            "+v"(a1[0].u4), "+v"(a1[1].u4), "+v"(a1[2].u4), "+v"(a1[3].u4),
            "+v"(a1[4].u4), "+v"(a1[5].u4), "+v"(a1[6].u4), "+v"(a1[7].u4)
          :: "memory");
        __builtin_amdgcn_sched_barrier(0);
        int ok = 1;
#pragma unroll
        for (int c = 0; c < 8; ++c)
#pragma unroll
          for (int d = 0; d < 4; ++d)
            ok &= (a0[c].dd[d] != SENT32) & (a1[c].dd[d] != SENT32);
        if (__all(ok)) break;
        if (++spins > (1 << 20)) break;    // hang-safety only
        if (spins > 8) __builtin_amdgcn_s_sleep(1);
      }
    }

    f32x4 acc[2][3];
#pragma unroll
    for (int m = 0; m < 2; ++m)
#pragma unroll
      for (int g = 0; g < 3; ++g)
#pragma unroll
        for (int u = 0; u < 4; ++u) acc[m][g][u] = 0.f;

#pragma unroll
    for (int c = 0; c < 8; ++c) if (c < ncha)
#pragma unroll
      for (int g = 0; g < 3; ++g) {
        acc[0][g] = __builtin_amdgcn_mfma_f32_16x16x32_bf16(a0[c].v, bw[g][c], acc[0][g], 0, 0, 0);
        acc[1][g] = __builtin_amdgcn_mfma_f32_16x16x32_bf16(a1[c].v, bw[g][c], acc[1][g], 0, 0, 0);
      }

#pragma unroll
    for (int m = 0; m < 2; ++m)
#pragma unroll
      for (int g = 0; g < 3; ++g)
        *(f32x4*)&part[(((w * 2 + m) * 3 + g) * 64 + lane) * 4] = acc[m][g];
    BAR_LGKM();                       // LDS writes visible; no vmem drain

    // ---- epilogue: 512 threads x 1 output; packed u32 store is the signal ----
    {
      float hr = 0.f, hz = 0.f, nx = 0.f, nh = 0.f;
#pragma unroll
      for (int ww = 0; ww < 8; ++ww) {
        int base = (ww * 2 + em) * 3;
        float vr = part[((base + 0) * 64 + eq2 * 16 + ejj) * 4 + ereg];
        float vz = part[((base + 1) * 64 + eq2 * 16 + ejj) * 4 + ereg];
        float vn = part[((base + 2) * 64 + eq2 * 16 + ejj) * 4 + ereg];
        hr += vr; hz += vz;
        if (ww < 4) nx += vn; else nh += vn;
      }
      float r  = __builtin_amdgcn_rcpf(1.f + __expf(-(hr + brv)));
      float z  = __builtin_amdgcn_rcpf(1.f + __expf(-(hz + bzv)));
      float a2 = nx + bnv + nh + r * nh;
      float nn = 1.f - 2.f * __builtin_amdgcn_rcpf(__expf(2.f * a2) + 1.f);  // tanh
      float hv = (1.f - z) * nn + z * phv;
      phv = hv;
      float other = __shfl_xor(hv, 1);   // partner tid^1 = same batch, ejj^1
      if ((ejj & 1) == 0) {
        unsigned int pk = (unsigned int)f2bf(hv) | ((unsigned int)f2bf(other) << 16);
        // single-writer, line-aligned 1KB region per (t, block)
        st_mall_b32(hxbuf + ((size_t)t * 64 + myblk) * 512 + eb * 16 + ejj, pk);
        if (L1)   // plain store for the final GEMM (never polled)
          *(unsigned int*)(y1 + ((size_t)t * B_ + eb) * H_ + j0 + ejj) = pk;
        if (t == S_ - 1) {
          hlast[eb * H_ + j0 + ejj]     = hv;
          hlast[eb * H_ + j0 + ejj + 1] = other;
        }
      }
    }
    BAR_LGKM();                       // part[] reads done; store acks NOT drained
  }
}

extern "C" void kernel_launch(void* const* d_in, const int* in_sizes, int n_in,
                              void* d_out, int out_size, void* d_ws, size_t ws_size,
                              hipStream_t stream) {
  const float* x    = (const float*)d_in[0];
  const float* Wih0 = (const float*)d_in[1];
  const float* Whh0 = (const float*)d_in[2];
  const float* b0   = (const float*)d_in[3];
  const float* Wih1 = (const float*)d_in[4];
  const float* Whh1 = (const float*)d_in[5];
  const float* b1   = (const float*)d_in[6];
  const float* Wlin = (const float*)d_in[7];
  const float* blin = (const float*)d_in[8];
  float* out = (float*)d_out;

  char* p = (char*)d_ws;
  size_t off = 0;
  auto alloc = [&](size_t bytes) { void* r = p + off; off += (bytes + 255) & ~(size_t)255; return r; };

  unsigned short* xtm   = (unsigned short*)alloc((size_t)8388608 * 2);   // (S,B,512) bf16
  unsigned short* wih0b = (unsigned short*)alloc((size_t)1572864 * 2);
  unsigned short* whh0b = (unsigned short*)alloc((size_t)3145728 * 2);
  unsigned short* wih1b = (unsigned short*)alloc((size_t)3145728 * 2);
  unsigned short* whh1b = (unsigned short*)alloc((size_t)3145728 * 2);
  unsigned short* wlinb = (unsigned short*)alloc((size_t)524288 * 2);
  unsigned short* hx0   = (unsigned short*)alloc((size_t)16777216 * 2);  // [S][64][32][16] bf16
  unsigned short* hx1   = (unsigned short*)alloc((size_t)16777216 * 2);  // [S][64][32][16] bf16
  unsigned short* y1b   = (unsigned short*)alloc((size_t)16777216 * 2);  // (S,B,H) bf16 (GEMM input)
  unsigned short* zerosB= (unsigned short*)alloc((size_t)B_ * H_ * 2);

  // poison exchange buffers: 0x7F7F bf16 sentinel (unreachable since |h|<1)
  (void)hipMemsetAsync(hx0, 0x7F, (size_t)16777216 * 2, stream);
  (void)hipMemsetAsync(hx1, 0x7F, (size_t)16777216 * 2, stream);
  (void)hipMemsetAsync(zerosB, 0, (size_t)B_ * H_ * 2, stream);

  auto cast = [&](const float* in, unsigned short* o, int n) {
    cast_f32_bf16<<<n / 256, 256, 0, stream>>>(in, o, n);
  };
  cast_transpose_x<<<16384, 128, 0, stream>>>(x, xtm);
  cast(Wih0, wih0b, 1572864);
  cast(Whh0, whh0b, 3145728);
  cast(Wih1, wih1b, 3145728);
  cast(Whh1, whh1b, 3145728);
  cast(Wlin, wlinb, 524288);

  float* hlast0 = out + 8388608;
  float* hlast1 = out + 8388608 + B_ * H_;

  gru_fused<<<128, 512, 0, stream>>>(wih0b, whh0b, b0, wih1b, whh1b, b1,
                                     xtm, zerosB, hx0, hx1, y1b, hlast0, hlast1);

  // final: out = y1 @ Wlin^T + blin, C rows -> (b,s)
  {
    dim3 g(512 / 128, 16384 / 128);
    gemm_bf16<0, 1, float><<<g, 256, 0, stream>>>(y1b, wlinb, blin, out, 16384, 512, 1024);
  }
}